// Round 2
// baseline (8142.435 us; speedup 1.0000x reference)
//
#include <hip/hip_runtime.h>
#include <cstdint>
#include <cstddef>

typedef unsigned short u16;
typedef unsigned int   u32;

// ---------------- bf16 helpers (bit-level) ----------------------------------
__device__ __forceinline__ float bf2f(u16 b) {
  union { u32 u; float f; } v; v.u = ((u32)b) << 16; return v.f;
}
__device__ __forceinline__ u16 f2bf(float f) {
  union { float f; u32 u; } v; v.f = f;
  u32 u = v.u;
  return (u16)((u + 0x7fffu + ((u >> 16) & 1u)) >> 16);  // RNE
}

// ---------------- dtype probe: bf16 vs f32 ----------------------------------
// x ~ N(0,1). As bf16, exponent field 0xFF never occurs. If the buffer is
// really f32, the LOW half-word of each float is random mantissa bits ->
// P(exp==0xFF) = 1/256 per half-word -> guaranteed hits in 8192 half-words.
__global__ void detect_dtype(const u16* __restrict__ xin, int* __restrict__ flag) {
  int hits = 0;
  for (int i = threadIdx.x; i < 16384; i += 256) {
    u16 v = xin[i];
    if (((v >> 7) & 0xFF) == 0xFF) hits++;
  }
  if (hits) atomicOr(flag, 1);
}

// ---------------- canonicalize a tensor to bf16 -----------------------------
__global__ __launch_bounds__(256) void convert_bf16(const void* __restrict__ src,
    u16* __restrict__ dst, int n, const int* __restrict__ flag) {
  int i = blockIdx.x * 256 + threadIdx.x;
  if (i >= n) return;
  if (*flag) dst[i] = f2bf(((const float*)src)[i]);
  else       dst[i] = ((const u16*)src)[i];
}

// ---------------- init: x_ws = f32(x_in[:, :64]), input row stride 65 -------
__global__ __launch_bounds__(256) void init_x(const void* __restrict__ xin,
    float* __restrict__ x, const int* __restrict__ flag, int N) {
  int idx = blockIdx.x * 256 + threadIdx.x;
  if (idx >= N * 64) return;
  int n = idx >> 6, c = idx & 63;
  size_t si = (size_t)n * 65 + c;
  float v = (*flag) ? ((const float*)xin)[si] : bf2f(((const u16*)xin)[si]);
  if (!isfinite(v)) v = 0.0f;   // no-op for valid inputs; kills NaN cascades
  x[idx] = v;
}

// ---------------- per-column sum & sumsq over N rows ------------------------
__global__ __launch_bounds__(256) void col_stats(const float* __restrict__ x,
                                                 float* __restrict__ stats, int N) {
  int c   = threadIdx.x & 63;
  int sub = threadIdx.x >> 6;          // 0..3
  int rows = N / gridDim.x;
  int r0 = blockIdx.x * rows;
  float s = 0.f, s2 = 0.f;
  for (int r = sub; r < rows; r += 4) {
    float v = x[(size_t)(r0 + r) * 64 + c];
    s += v; s2 = fmaf(v, v, s2);
  }
  __shared__ float ls[256], lq[256];
  ls[threadIdx.x] = s; lq[threadIdx.x] = s2;
  __syncthreads();
  if (threadIdx.x < 64) {
    s  = ls[c] + ls[c + 64] + ls[c + 128] + ls[c + 192];
    s2 = lq[c] + lq[c + 64] + lq[c + 128] + lq[c + 192];
    atomicAdd(&stats[c], s);
    atomicAdd(&stats[64 + c], s2);
  }
}

// ---------------- normalize in place + extract contiguous x1 (bf16) --------
__global__ __launch_bounds__(256) void normalize_split(float* __restrict__ x,
    const float* __restrict__ stats, u16* __restrict__ x1, int off, int N) {
  int idx = blockIdx.x * 256 + threadIdx.x;
  if (idx >= N * 64) return;
  int c = idx & 63;
  float invN = 1.0f / (float)N;
  float mu  = stats[c] * invN;
  float var = stats[64 + c] * invN - mu * mu;
  var = fmaxf(var, 0.0f);               // numeric guard (no-op normally)
  float rs  = 1.0f / sqrtf(var + 1e-5f);
  float v = (x[idx] - mu) * rs;
  x[idx] = v;
  int cc = c - off;
  if (cc >= 0 && cc < 32) x1[((size_t)(idx >> 6)) * 32 + cc] = f2bf(v);
}

// ---------------- GEMM: C[M,O] = act(A[M,K] @ W[O,K]^T + b) -----------------
// A,W,b bf16; C bf16 or f32. Tile 128x128, 8x8/thread in 2x2 quadrants.
template<bool RELU, bool OUTBF>
__global__ __launch_bounds__(256) void gemm_tn(
    const u16* __restrict__ A, const u16* __restrict__ W,
    const u16* __restrict__ bias, void* __restrict__ Cv, int K, int O) {
  __shared__ __align__(16) float Ast[32][132];
  __shared__ __align__(16) float Wst[32][132];
  const int tid = threadIdx.x;
  const int bo = blockIdx.x * 128;
  const int bm = blockIdx.y * 128;
  const int tx = tid & 15, ty = tid >> 4;
  const int lr = tid >> 2;                 // 0..63
  const int lk = (tid & 3) * 8;            // 0,8,16,24
  float acc[8][8] = {};

  const size_t aRow0 = (size_t)(bm + lr) * K + lk;
  const size_t aRow1 = (size_t)(bm + lr + 64) * K + lk;
  const int wr0 = bo + lr, wr1 = bo + lr + 64;
  const size_t wRow0 = (size_t)wr0 * K + lk;
  const size_t wRow1 = (size_t)wr1 * K + lk;

  for (int kc = 0; kc < K; kc += 32) {
    uint4 a0 = *(const uint4*)(A + aRow0 + kc);
    uint4 a1 = *(const uint4*)(A + aRow1 + kc);
    uint4 w0 = make_uint4(0u, 0u, 0u, 0u);
    uint4 w1 = make_uint4(0u, 0u, 0u, 0u);
    if (wr0 < O) w0 = *(const uint4*)(W + wRow0 + kc);
    if (wr1 < O) w1 = *(const uint4*)(W + wRow1 + kc);
    const u32* ap0 = (const u32*)&a0; const u32* ap1 = (const u32*)&a1;
    const u32* wp0 = (const u32*)&w0; const u32* wp1 = (const u32*)&w1;
    #pragma unroll
    for (int q = 0; q < 4; ++q) {
      Ast[lk + 2*q    ][lr]      = bf2f((u16)(ap0[q] & 0xffffu));
      Ast[lk + 2*q + 1][lr]      = bf2f((u16)(ap0[q] >> 16));
      Ast[lk + 2*q    ][lr + 64] = bf2f((u16)(ap1[q] & 0xffffu));
      Ast[lk + 2*q + 1][lr + 64] = bf2f((u16)(ap1[q] >> 16));
      Wst[lk + 2*q    ][lr]      = bf2f((u16)(wp0[q] & 0xffffu));
      Wst[lk + 2*q + 1][lr]      = bf2f((u16)(wp0[q] >> 16));
      Wst[lk + 2*q    ][lr + 64] = bf2f((u16)(wp1[q] & 0xffffu));
      Wst[lk + 2*q + 1][lr + 64] = bf2f((u16)(wp1[q] >> 16));
    }
    __syncthreads();
    #pragma unroll 8
    for (int k = 0; k < 32; ++k) {
      float4 aLo = *(const float4*)&Ast[k][ty * 4];
      float4 aHi = *(const float4*)&Ast[k][ty * 4 + 64];
      float4 bLo = *(const float4*)&Wst[k][tx * 4];
      float4 bHi = *(const float4*)&Wst[k][tx * 4 + 64];
      float a[8] = {aLo.x, aLo.y, aLo.z, aLo.w, aHi.x, aHi.y, aHi.z, aHi.w};
      float b[8] = {bLo.x, bLo.y, bLo.z, bLo.w, bHi.x, bHi.y, bHi.z, bHi.w};
      #pragma unroll
      for (int i = 0; i < 8; ++i)
        #pragma unroll
        for (int j = 0; j < 8; ++j)
          acc[i][j] = fmaf(a[i], b[j], acc[i][j]);
    }
    __syncthreads();
  }

  #pragma unroll
  for (int jh = 0; jh < 2; ++jh) {
    int col0 = bo + jh * 64 + tx * 4;
    if (col0 >= O) continue;
    float bb[4];
    #pragma unroll
    for (int j = 0; j < 4; ++j) bb[j] = bf2f(bias[col0 + j]);
    #pragma unroll
    for (int ih = 0; ih < 2; ++ih) {
      #pragma unroll
      for (int i = 0; i < 4; ++i) {
        int row = bm + ih * 64 + ty * 4 + i;
        float v[4];
        #pragma unroll
        for (int j = 0; j < 4; ++j) {
          float t = acc[ih * 4 + i][jh * 4 + j] + bb[j];
          if (RELU) t = fmaxf(t, 0.0f);
          v[j] = t;
        }
        if (OUTBF) {
          u16* C = (u16*)Cv;
          ushort4 o;
          o.x = f2bf(v[0]); o.y = f2bf(v[1]); o.z = f2bf(v[2]); o.w = f2bf(v[3]);
          *(ushort4*)(C + (size_t)row * O + col0) = o;
        } else {
          float* C = (float*)Cv;
          *(float4*)(C + (size_t)row * O + col0) = make_float4(v[0], v[1], v[2], v[3]);
        }
      }
    }
  }
}

// ---------------- coupling on a row chunk -----------------------------------
__global__ __launch_bounds__(256) void coupling(float* __restrict__ x,
    const float* __restrict__ s, const float* __restrict__ t,
    float* __restrict__ det, int off1, int first, int r0, int nc) {
  int gid = blockIdx.x * 256 + threadIdx.x;
  int nl = gid >> 5, j = gid & 31;
  if (nl >= nc) return;
  int n = r0 + nl;
  int off2 = 32 - off1;
  size_t rb = (size_t)n * 64;
  float x1v = x[rb + off1 + j];
  float x2v = x[rb + off2 + j];
  float sv = s[(size_t)nl * 32 + j];
  float tv = t[(size_t)nl * 32 + j];
  float e = expf(fminf(sv, 30.0f));     // clamp is a no-op when correct
  float y2 = fmaf(x2v, e, tv);
  x[rb + j]      = x1v;
  x[rb + 32 + j] = y2;
  float r = sv;
  #pragma unroll
  for (int o = 16; o > 0; o >>= 1) r += __shfl_down(r, o, 32);
  if (j == 0) { if (first) det[n] = r; else det[n] += r; }
}

// ---------------- GMM log-likelihood + output writes + partial sums ---------
__global__ __launch_bounds__(256) void gmm_out(const float* __restrict__ x,
    const float* __restrict__ det, const u16* __restrict__ means,
    void* __restrict__ outv, double* __restrict__ acc,
    const int* __restrict__ flag, int N) {
  __shared__ float ms[640];
  __shared__ double rll[256], rdt[256];
  for (int i = threadIdx.x; i < 640; i += 256) ms[i] = bf2f(means[i]);
  __syncthreads();
  int of32 = *flag;
  int n = blockIdx.x * 256 + threadIdx.x;
  double llv = 0.0, dtv = 0.0;
  if (n < N) {
    float y[64];
    size_t rb = (size_t)n * 64;
    #pragma unroll
    for (int c = 0; c < 64; ++c) y[c] = x[rb + c];
    if (of32) {
      float* out = (float*)outv;
      #pragma unroll
      for (int c = 0; c < 64; ++c) out[rb + c] = y[c];
    } else {
      u16* out = (u16*)outv;
      #pragma unroll
      for (int c = 0; c < 64; ++c) out[rb + c] = f2bf(y[c]);
    }
    float lp[10];
    float mx = -3.0e38f;
    #pragma unroll
    for (int k = 0; k < 10; ++k) {
      float d2 = 0.0f;
      #pragma unroll
      for (int c = 0; c < 64; ++c) { float d = y[c] - ms[k * 64 + c]; d2 = fmaf(d, d, d2); }
      float v = -0.5f * (d2 + 64.0f * 1.8378770664093455f) - 2.302585092994046f;
      lp[k] = v; mx = fmaxf(mx, v);
    }
    float se = 0.0f;
    #pragma unroll
    for (int k = 0; k < 10; ++k) se += expf(lp[k] - mx);
    float ll = mx + logf(se);
    float dv = det[n];
    size_t NY = (size_t)N * 64;
    if (of32) {
      float* out = (float*)outv;
      out[NY + 1 + n]     = ll;
      out[NY + 1 + N + n] = dv;
    } else {
      u16* out = (u16*)outv;
      out[NY + 1 + n]     = f2bf(ll);
      out[NY + 1 + N + n] = f2bf(dv);
    }
    llv = ll; dtv = dv;
  }
  rll[threadIdx.x] = llv; rdt[threadIdx.x] = dtv;
  __syncthreads();
  for (int st = 128; st > 0; st >>= 1) {
    if (threadIdx.x < st) {
      rll[threadIdx.x] += rll[threadIdx.x + st];
      rdt[threadIdx.x] += rdt[threadIdx.x + st];
    }
    __syncthreads();
  }
  if (threadIdx.x == 0) { atomicAdd(&acc[0], rll[0]); atomicAdd(&acc[1], rdt[0]); }
}

// ---------------- scalars: loss, ll.mean, det.mean --------------------------
__global__ void finalize(const double* __restrict__ acc, void* __restrict__ outv,
                         const int* __restrict__ flag, int N) {
  double llm = acc[0] / (double)N;
  double dm  = acc[1] / (double)N;
  size_t NY = (size_t)N * 64;
  if (*flag) {
    float* out = (float*)outv;
    out[NY]                         = (float)(-(llm + dm));
    out[NY + 1 + 2 * (size_t)N]     = (float)llm;
    out[NY + 1 + 2 * (size_t)N + 1] = (float)dm;
  } else {
    u16* out = (u16*)outv;
    out[NY]                         = f2bf((float)(-(llm + dm)));
    out[NY + 1 + 2 * (size_t)N]     = f2bf((float)llm);
    out[NY + 1 + 2 * (size_t)N + 1] = f2bf((float)dm);
  }
}

// ============================================================================
extern "C" void kernel_launch(void* const* d_in, const int* in_sizes, int n_in,
                              void* d_out, int out_size, void* d_ws, size_t ws_size,
                              hipStream_t stream) {
  const int N = in_sizes[0] / 65;              // 65536
  (void)n_in; (void)out_size;

  // ---- workspace carve-up: small fixed buffers first, chunked MLP last ----
  char* ws = (char*)d_ws;
  size_t off = 0;
  auto alloc = [&](size_t bytes) -> void* {
    void* p = ws + off; off = (off + bytes + 255) & ~(size_t)255; return p;
  };
  int*    flag  = (int*)   alloc(4);
  double* acc   = (double*)alloc(2 * 8);
  float*  stats = (float*) alloc(128 * 4);
  float*  det   = (float*) alloc((size_t)N * 4);
  float*  x     = (float*) alloc((size_t)N * 64 * 4);
  u16*    x1    = (u16*)   alloc((size_t)N * 32 * 2);

  // canonical bf16 weights (converted every launch; ~9.5 MB)
  static const int wcnt[13] = {
    8*512*32, 8*512, 8*512*512, 8*512, 8*32*512, 8*32,   // s-path
    8*512*32, 8*512, 8*512*512, 8*512, 8*32*512, 8*32,   // t-path
    10*64                                                // means
  };
  u16* wptr[13];
  for (int t = 0; t < 13; ++t) wptr[t] = (u16*)alloc((size_t)wcnt[t] * 2);

  // chunked h0/h1/sbuf/tbuf: pick largest Nc (multiple of 128) that fits
  size_t fixed = off;
  size_t budget = (ws_size > fixed) ? (ws_size - fixed - 4096) : 0;
  long long ncl = (long long)(budget / 2304);  // per-row: 2*512*2 + 2*32*4
  int Nc = (int)((ncl / 128) * 128);
  if (Nc < 128) Nc = 128;
  if (Nc > N)   Nc = N;
  u16*   h0   = (u16*)  alloc((size_t)Nc * 512 * 2);
  u16*   h1   = (u16*)  alloc((size_t)Nc * 512 * 2);
  float* sbuf = (float*)alloc((size_t)Nc * 32 * 4);
  float* tbuf = (float*)alloc((size_t)Nc * 32 * 4);

  // ---- dtype probe + canonicalize ----
  hipMemsetAsync(flag, 0, 4, stream);
  detect_dtype<<<dim3(1), dim3(256), 0, stream>>>((const u16*)d_in[0], flag);
  for (int t = 0; t < 13; ++t) {
    int n = wcnt[t];
    convert_bf16<<<dim3((n + 255) / 256), dim3(256), 0, stream>>>(
        d_in[t + 1], wptr[t], n, flag);
  }

  const int NE = N * 64;
  init_x<<<dim3((NE + 255) / 256), dim3(256), 0, stream>>>(d_in[0], x, flag, N);

  for (int i = 0; i < 8; ++i) {
    hipMemsetAsync(stats, 0, 128 * sizeof(float), stream);
    col_stats<<<dim3(256), dim3(256), 0, stream>>>(x, stats, N);
    const int off1 = (i & 1) ? 32 : 0;
    normalize_split<<<dim3((NE + 255) / 256), dim3(256), 0, stream>>>(x, stats, x1, off1, N);

    const u16* W0s = wptr[0] + (size_t)i * 512 * 32;  const u16* B0s = wptr[1] + (size_t)i * 512;
    const u16* W1s = wptr[2] + (size_t)i * 512 * 512; const u16* B1s = wptr[3] + (size_t)i * 512;
    const u16* W2s = wptr[4] + (size_t)i * 32 * 512;  const u16* B2s = wptr[5] + (size_t)i * 32;
    const u16* W0t = wptr[6] + (size_t)i * 512 * 32;  const u16* B0t = wptr[7] + (size_t)i * 512;
    const u16* W1t = wptr[8] + (size_t)i * 512 * 512; const u16* B1t = wptr[9] + (size_t)i * 512;
    const u16* W2t = wptr[10] + (size_t)i * 32 * 512; const u16* B2t = wptr[11] + (size_t)i * 32;

    for (int r0 = 0; r0 < N; r0 += Nc) {
      int nc = (N - r0 < Nc) ? (N - r0) : Nc;
      dim3 gBig(4, nc / 128), gSmall(1, nc / 128), blk(256);
      const u16* xc = x1 + (size_t)r0 * 32;
      // s path
      gemm_tn<true,  true ><<<gBig,   blk, 0, stream>>>(xc, W0s, B0s, h0,   32, 512);
      gemm_tn<true,  true ><<<gBig,   blk, 0, stream>>>(h0, W1s, B1s, h1,  512, 512);
      gemm_tn<false, false><<<gSmall, blk, 0, stream>>>(h1, W2s, B2s, sbuf, 512, 32);
      // t path
      gemm_tn<true,  true ><<<gBig,   blk, 0, stream>>>(xc, W0t, B0t, h0,   32, 512);
      gemm_tn<true,  true ><<<gBig,   blk, 0, stream>>>(h0, W1t, B1t, h1,  512, 512);
      gemm_tn<false, false><<<gSmall, blk, 0, stream>>>(h1, W2t, B2t, tbuf, 512, 32);

      coupling<<<dim3((nc * 32 + 255) / 256), dim3(256), 0, stream>>>(
          x, sbuf, tbuf, det, off1, (i == 0) ? 1 : 0, r0, nc);
    }
  }

  hipMemsetAsync(acc, 0, 2 * sizeof(double), stream);
  gmm_out<<<dim3((N + 255) / 256), dim3(256), 0, stream>>>(x, det, wptr[12],
                                                           d_out, acc, flag, N);
  finalize<<<dim3(1), dim3(1), 0, stream>>>(acc, d_out, flag, N);
}

// Round 3
// 2184.682 us; speedup vs baseline: 3.7271x; 3.7271x over previous
//
#include <hip/hip_runtime.h>
#include <cstdint>
#include <cstddef>

typedef unsigned short u16;
typedef unsigned int   u32;
typedef __attribute__((ext_vector_type(8))) short short8;   // 8 bf16 = 4 VGPRs
typedef __attribute__((ext_vector_type(4))) float f32x4;

// ---------------- bf16 helpers (bit-level) ----------------------------------
__device__ __forceinline__ float bf2f(u16 b) {
  union { u32 u; float f; } v; v.u = ((u32)b) << 16; return v.f;
}
__device__ __forceinline__ u16 f2bf(float f) {
  union { float f; u32 u; } v; v.f = f;
  u32 u = v.u;
  return (u16)((u + 0x7fffu + ((u >> 16) & 1u)) >> 16);  // RNE
}

// ---------------- dtype probe: bf16 vs f32 ----------------------------------
__global__ void detect_dtype(const u16* __restrict__ xin, int* __restrict__ flag) {
  int hits = 0;
  for (int i = threadIdx.x; i < 16384; i += 256) {
    u16 v = xin[i];
    if (((v >> 7) & 0xFF) == 0xFF) hits++;
  }
  if (hits) atomicOr(flag, 1);
}

// ---------------- canonicalize a tensor to bf16 -----------------------------
__global__ __launch_bounds__(256) void convert_bf16(const void* __restrict__ src,
    u16* __restrict__ dst, int n, const int* __restrict__ flag) {
  int i = blockIdx.x * 256 + threadIdx.x;
  if (i >= n) return;
  if (*flag) dst[i] = f2bf(((const float*)src)[i]);
  else       dst[i] = ((const u16*)src)[i];
}

// ---------------- init: x_ws = f32(x_in[:, :64]), input row stride 65 -------
__global__ __launch_bounds__(256) void init_x(const void* __restrict__ xin,
    float* __restrict__ x, const int* __restrict__ flag, int N) {
  int idx = blockIdx.x * 256 + threadIdx.x;
  if (idx >= N * 64) return;
  int n = idx >> 6, c = idx & 63;
  size_t si = (size_t)n * 65 + c;
  float v = (*flag) ? ((const float*)xin)[si] : bf2f(((const u16*)xin)[si]);
  if (!isfinite(v)) v = 0.0f;
  x[idx] = v;
}

// ---------------- per-column sum & sumsq over N rows ------------------------
__global__ __launch_bounds__(256) void col_stats(const float* __restrict__ x,
                                                 float* __restrict__ stats, int N) {
  int c   = threadIdx.x & 63;
  int sub = threadIdx.x >> 6;
  int rows = N / gridDim.x;
  int r0 = blockIdx.x * rows;
  float s = 0.f, s2 = 0.f;
  for (int r = sub; r < rows; r += 4) {
    float v = x[(size_t)(r0 + r) * 64 + c];
    s += v; s2 = fmaf(v, v, s2);
  }
  __shared__ float ls[256], lq[256];
  ls[threadIdx.x] = s; lq[threadIdx.x] = s2;
  __syncthreads();
  if (threadIdx.x < 64) {
    s  = ls[c] + ls[c + 64] + ls[c + 128] + ls[c + 192];
    s2 = lq[c] + lq[c + 64] + lq[c + 128] + lq[c + 192];
    atomicAdd(&stats[c], s);
    atomicAdd(&stats[64 + c], s2);
  }
}

// ---------------- normalize in place + extract contiguous x1 (bf16) --------
__global__ __launch_bounds__(256) void normalize_split(float* __restrict__ x,
    const float* __restrict__ stats, u16* __restrict__ x1, int off, int N) {
  int idx = blockIdx.x * 256 + threadIdx.x;
  if (idx >= N * 64) return;
  int c = idx & 63;
  float invN = 1.0f / (float)N;
  float mu  = stats[c] * invN;
  float var = stats[64 + c] * invN - mu * mu;
  var = fmaxf(var, 0.0f);
  float rs  = 1.0f / sqrtf(var + 1e-5f);
  float v = (x[idx] - mu) * rs;
  x[idx] = v;
  int cc = c - off;
  if (cc >= 0 && cc < 32) x1[((size_t)(idx >> 6)) * 32 + cc] = f2bf(v);
}

// ---------------- MFMA GEMM: C[M,O] = act(A[M,K] @ W[O,K]^T + b) ------------
// A[M,K], W[O,K] bf16 row-major (both K-contiguous -> identical frag loads).
// Block 256 thr = 4 waves. BK=32 (one 16x16x32 MFMA K-step).
// Wave grid WR x WC (WR*WC=4); wave tile (BM/WR) x (BO/WC); frags 16x16.
// LDS stride 40 elts (80 B = 20 banks): frag ds_read_b128 -> 2-way = free.
template<bool RELU, bool OUTBF, int BM, int BO, int WR, int WC>
__global__ __launch_bounds__(256) void gemm_mfma(
    const u16* __restrict__ A, const u16* __restrict__ W,
    const u16* __restrict__ bias, void* __restrict__ Cv, int K, int O) {
  constexpr int FM = (BM / WR) / 16;
  constexpr int FO = (BO / WC) / 16;
  __shared__ __align__(16) u16 As[BM][40];
  __shared__ __align__(16) u16 Ws[BO][40];

  const int tid  = threadIdx.x;
  const int lane = tid & 63;
  const int wave = tid >> 6;
  const int bo = blockIdx.x * BO;
  const int bm = blockIdx.y * BM;
  const int wm0 = (wave % WR) * (BM / WR);
  const int wo0 = (wave / WR) * (BO / WC);
  const int m = lane & 15, q = lane >> 4;

  f32x4 acc[FM][FO];
  const f32x4 zero = {0.f, 0.f, 0.f, 0.f};
  #pragma unroll
  for (int i = 0; i < FM; ++i)
    #pragma unroll
    for (int j = 0; j < FO; ++j) acc[i][j] = zero;

  // staging address precompute
  const int ar = tid >> 2, ac = (tid & 3) * 8;

  for (int kc = 0; kc < K; kc += 32) {
    #pragma unroll
    for (int it = 0; it < BM / 64; ++it) {
      int r = it * 64 + ar;
      *(uint4*)&As[r][ac] = *(const uint4*)(A + (size_t)(bm + r) * K + kc + ac);
    }
    if constexpr (BO >= 64) {
      #pragma unroll
      for (int it = 0; it < BO / 64; ++it) {
        int r = it * 64 + ar;
        *(uint4*)&Ws[r][ac] = *(const uint4*)(W + (size_t)(bo + r) * K + kc + ac);
      }
    } else {
      if (tid < BO * 4)
        *(uint4*)&Ws[ar][ac] = *(const uint4*)(W + (size_t)(bo + ar) * K + kc + ac);
    }
    __syncthreads();

    short8 af[FM], wf[FO];
    #pragma unroll
    for (int fm = 0; fm < FM; ++fm)
      af[fm] = *(const short8*)&As[wm0 + fm * 16 + m][q * 8];
    #pragma unroll
    for (int fo = 0; fo < FO; ++fo)
      wf[fo] = *(const short8*)&Ws[wo0 + fo * 16 + m][q * 8];
    #pragma unroll
    for (int fm = 0; fm < FM; ++fm)
      #pragma unroll
      for (int fo = 0; fo < FO; ++fo)
        acc[fm][fo] = __builtin_amdgcn_mfma_f32_16x16x32_bf16(
            af[fm], wf[fo], acc[fm][fo], 0, 0, 0);
    __syncthreads();
  }

  // epilogue: C/D layout col=lane&15, row=(lane>>4)*4+i  [m89/m91-verified]
  #pragma unroll
  for (int fo = 0; fo < FO; ++fo) {
    int col = bo + wo0 + fo * 16 + m;
    float bb = bf2f(bias[col]);
    #pragma unroll
    for (int fm = 0; fm < FM; ++fm) {
      #pragma unroll
      for (int i = 0; i < 4; ++i) {
        int row = bm + wm0 + fm * 16 + q * 4 + i;
        float v = acc[fm][fo][i] + bb;
        if (RELU) v = fmaxf(v, 0.0f);
        if (OUTBF) ((u16*)Cv)[(size_t)row * O + col] = f2bf(v);
        else       ((float*)Cv)[(size_t)row * O + col] = v;
      }
    }
  }
}

// ---------------- coupling on a row chunk -----------------------------------
__global__ __launch_bounds__(256) void coupling(float* __restrict__ x,
    const float* __restrict__ s, const float* __restrict__ t,
    float* __restrict__ det, int off1, int first, int r0, int nc) {
  int gid = blockIdx.x * 256 + threadIdx.x;
  int nl = gid >> 5, j = gid & 31;
  if (nl >= nc) return;
  int n = r0 + nl;
  int off2 = 32 - off1;
  size_t rb = (size_t)n * 64;
  float x1v = x[rb + off1 + j];
  float x2v = x[rb + off2 + j];
  float sv = s[(size_t)nl * 32 + j];
  float tv = t[(size_t)nl * 32 + j];
  float e = expf(fminf(sv, 30.0f));
  float y2 = fmaf(x2v, e, tv);
  x[rb + j]      = x1v;
  x[rb + 32 + j] = y2;
  float r = sv;
  #pragma unroll
  for (int o = 16; o > 0; o >>= 1) r += __shfl_down(r, o, 32);
  if (j == 0) { if (first) det[n] = r; else det[n] += r; }
}

// ---------------- GMM log-likelihood + output writes + partial sums ---------
__global__ __launch_bounds__(256) void gmm_out(const float* __restrict__ x,
    const float* __restrict__ det, const u16* __restrict__ means,
    void* __restrict__ outv, double* __restrict__ acc,
    const int* __restrict__ flag, int N) {
  __shared__ float ms[640];
  __shared__ double rll[256], rdt[256];
  for (int i = threadIdx.x; i < 640; i += 256) ms[i] = bf2f(means[i]);
  __syncthreads();
  int of32 = *flag;
  int n = blockIdx.x * 256 + threadIdx.x;
  double llv = 0.0, dtv = 0.0;
  if (n < N) {
    float y[64];
    size_t rb = (size_t)n * 64;
    #pragma unroll
    for (int c = 0; c < 64; ++c) y[c] = x[rb + c];
    if (of32) {
      float* out = (float*)outv;
      #pragma unroll
      for (int c = 0; c < 64; ++c) out[rb + c] = y[c];
    } else {
      u16* out = (u16*)outv;
      #pragma unroll
      for (int c = 0; c < 64; ++c) out[rb + c] = f2bf(y[c]);
    }
    float lp[10];
    float mx = -3.0e38f;
    #pragma unroll
    for (int k = 0; k < 10; ++k) {
      float d2 = 0.0f;
      #pragma unroll
      for (int c = 0; c < 64; ++c) { float d = y[c] - ms[k * 64 + c]; d2 = fmaf(d, d, d2); }
      float v = -0.5f * (d2 + 64.0f * 1.8378770664093455f) - 2.302585092994046f;
      lp[k] = v; mx = fmaxf(mx, v);
    }
    float se = 0.0f;
    #pragma unroll
    for (int k = 0; k < 10; ++k) se += expf(lp[k] - mx);
    float ll = mx + logf(se);
    float dv = det[n];
    size_t NY = (size_t)N * 64;
    if (of32) {
      float* out = (float*)outv;
      out[NY + 1 + n]     = ll;
      out[NY + 1 + N + n] = dv;
    } else {
      u16* out = (u16*)outv;
      out[NY + 1 + n]     = f2bf(ll);
      out[NY + 1 + N + n] = f2bf(dv);
    }
    llv = ll; dtv = dv;
  }
  rll[threadIdx.x] = llv; rdt[threadIdx.x] = dtv;
  __syncthreads();
  for (int st = 128; st > 0; st >>= 1) {
    if (threadIdx.x < st) {
      rll[threadIdx.x] += rll[threadIdx.x + st];
      rdt[threadIdx.x] += rdt[threadIdx.x + st];
    }
    __syncthreads();
  }
  if (threadIdx.x == 0) { atomicAdd(&acc[0], rll[0]); atomicAdd(&acc[1], rdt[0]); }
}

// ---------------- scalars: loss, ll.mean, det.mean --------------------------
__global__ void finalize(const double* __restrict__ acc, void* __restrict__ outv,
                         const int* __restrict__ flag, int N) {
  double llm = acc[0] / (double)N;
  double dm  = acc[1] / (double)N;
  size_t NY = (size_t)N * 64;
  if (*flag) {
    float* out = (float*)outv;
    out[NY]                         = (float)(-(llm + dm));
    out[NY + 1 + 2 * (size_t)N]     = (float)llm;
    out[NY + 1 + 2 * (size_t)N + 1] = (float)dm;
  } else {
    u16* out = (u16*)outv;
    out[NY]                         = f2bf((float)(-(llm + dm)));
    out[NY + 1 + 2 * (size_t)N]     = f2bf((float)llm);
    out[NY + 1 + 2 * (size_t)N + 1] = f2bf((float)dm);
  }
}

// ============================================================================
extern "C" void kernel_launch(void* const* d_in, const int* in_sizes, int n_in,
                              void* d_out, int out_size, void* d_ws, size_t ws_size,
                              hipStream_t stream) {
  const int N = in_sizes[0] / 65;              // 65536
  (void)n_in; (void)out_size;

  char* ws = (char*)d_ws;
  size_t off = 0;
  auto alloc = [&](size_t bytes) -> void* {
    void* p = ws + off; off = (off + bytes + 255) & ~(size_t)255; return p;
  };
  int*    flag  = (int*)   alloc(4);
  double* acc   = (double*)alloc(2 * 8);
  float*  stats = (float*) alloc(128 * 4);
  float*  det   = (float*) alloc((size_t)N * 4);
  float*  x     = (float*) alloc((size_t)N * 64 * 4);
  u16*    x1    = (u16*)   alloc((size_t)N * 32 * 2);

  static const int wcnt[13] = {
    8*512*32, 8*512, 8*512*512, 8*512, 8*32*512, 8*32,
    8*512*32, 8*512, 8*512*512, 8*512, 8*32*512, 8*32,
    10*64
  };
  u16* wptr[13];
  for (int t = 0; t < 13; ++t) wptr[t] = (u16*)alloc((size_t)wcnt[t] * 2);

  // chunked h0/h1/sbuf/tbuf: largest Nc (multiple of 256) that fits
  size_t fixed = off;
  size_t budget = (ws_size > fixed) ? (ws_size - fixed - 4096) : 0;
  long long ncl = (long long)(budget / 2304);  // per-row: 2*512*2 + 2*32*4
  int Nc = (int)((ncl / 256) * 256);
  if (Nc < 256) Nc = 256;
  if (Nc > N)   Nc = N;
  u16*   h0   = (u16*)  alloc((size_t)Nc * 512 * 2);
  u16*   h1   = (u16*)  alloc((size_t)Nc * 512 * 2);
  float* sbuf = (float*)alloc((size_t)Nc * 32 * 4);
  float* tbuf = (float*)alloc((size_t)Nc * 32 * 4);

  // ---- dtype probe + canonicalize ----
  hipMemsetAsync(flag, 0, 4, stream);
  detect_dtype<<<dim3(1), dim3(256), 0, stream>>>((const u16*)d_in[0], flag);
  for (int t = 0; t < 13; ++t) {
    int n = wcnt[t];
    convert_bf16<<<dim3((n + 255) / 256), dim3(256), 0, stream>>>(
        d_in[t + 1], wptr[t], n, flag);
  }

  const int NE = N * 64;
  init_x<<<dim3((NE + 255) / 256), dim3(256), 0, stream>>>(d_in[0], x, flag, N);

  for (int i = 0; i < 8; ++i) {
    hipMemsetAsync(stats, 0, 128 * sizeof(float), stream);
    col_stats<<<dim3(256), dim3(256), 0, stream>>>(x, stats, N);
    const int off1 = (i & 1) ? 32 : 0;
    normalize_split<<<dim3((NE + 255) / 256), dim3(256), 0, stream>>>(x, stats, x1, off1, N);

    const u16* W0s = wptr[0] + (size_t)i * 512 * 32;  const u16* B0s = wptr[1] + (size_t)i * 512;
    const u16* W1s = wptr[2] + (size_t)i * 512 * 512; const u16* B1s = wptr[3] + (size_t)i * 512;
    const u16* W2s = wptr[4] + (size_t)i * 32 * 512;  const u16* B2s = wptr[5] + (size_t)i * 32;
    const u16* W0t = wptr[6] + (size_t)i * 512 * 32;  const u16* B0t = wptr[7] + (size_t)i * 512;
    const u16* W1t = wptr[8] + (size_t)i * 512 * 512; const u16* B1t = wptr[9] + (size_t)i * 512;
    const u16* W2t = wptr[10] + (size_t)i * 32 * 512; const u16* B2t = wptr[11] + (size_t)i * 32;

    for (int r0 = 0; r0 < N; r0 += Nc) {
      int nc = (N - r0 < Nc) ? (N - r0) : Nc;
      dim3 gBig(4, nc / 128), gSmall(1, nc / 256), blk(256);
      const u16* xc = x1 + (size_t)r0 * 32;
      // s path
      gemm_mfma<true,  true,  128, 128, 2, 2><<<gBig,   blk, 0, stream>>>(xc, W0s, B0s, h0,   32, 512);
      gemm_mfma<true,  true,  128, 128, 2, 2><<<gBig,   blk, 0, stream>>>(h0, W1s, B1s, h1,  512, 512);
      gemm_mfma<false, false, 256,  32, 4, 1><<<gSmall, blk, 0, stream>>>(h1, W2s, B2s, sbuf, 512, 32);
      // t path
      gemm_mfma<true,  true,  128, 128, 2, 2><<<gBig,   blk, 0, stream>>>(xc, W0t, B0t, h0,   32, 512);
      gemm_mfma<true,  true,  128, 128, 2, 2><<<gBig,   blk, 0, stream>>>(h0, W1t, B1t, h1,  512, 512);
      gemm_mfma<false, false, 256,  32, 4, 1><<<gSmall, blk, 0, stream>>>(h1, W2t, B2t, tbuf, 512, 32);

      coupling<<<dim3((nc * 32 + 255) / 256), dim3(256), 0, stream>>>(
          x, sbuf, tbuf, det, off1, (i == 0) ? 1 : 0, r0, nc);
    }
  }

  hipMemsetAsync(acc, 0, 2 * sizeof(double), stream);
  gmm_out<<<dim3((N + 255) / 256), dim3(256), 0, stream>>>(x, det, wptr[12],
                                                           d_out, acc, flag, N);
  finalize<<<dim3(1), dim3(1), 0, stream>>>(acc, d_out, flag, N);
}